// Round 3
// baseline (1959.827 us; speedup 1.0000x reference)
//
#include <hip/hip_runtime.h>
#include <math.h>

// ---------------- constants ----------------
#define MS 128
#define MV 64
#define RBF 32
#define HID 32
#define TPW 384           // MS+MS+MV+MV
#define OS 256
#define OV 128

__device__ __forceinline__ float sspf(float x) {
    // softplus(x) - log(2), numerically stable
    float r = (x > 0.0f) ? (x + log1pf(expf(-x))) : log1pf(expf(x));
    return r - 0.6931471805599453f;
}
__device__ __forceinline__ float siluf(float x) {
    return x / (1.0f + expf(-x));
}

__constant__ float INV_S128 = 0.08838834764831845f;
__constant__ float INV_S64  = 0.125f;
__constant__ float INV_S320 = 0.05590169943749474f;
__constant__ float INV_S32  = 0.17677669529663687f;
__constant__ float INV_S192 = 0.07216878364870323f;
#define C1F 0.8660254037844386f
#define INV_S3F 0.5773502691896258f

// ---------------- K00: zero the scatter accumulator ----------------
__global__ void k_zero(float4* __restrict__ p, int n4) {
    int i = blockIdx.x * blockDim.x + threadIdx.x;
    int stride = gridDim.x * blockDim.x;
    float4 z = make_float4(0.f, 0.f, 0.f, 0.f);
    for (; i < n4; i += stride) p[i] = z;
}

// ---------------- K0: fold Wl1 rows 0..127 + 128..255 ----------------
__global__ void k_prep(const float* __restrict__ Wl1, float* __restrict__ Wl1p) {
    int i = blockIdx.x * blockDim.x + threadIdx.x;
    if (i < 128 * 32) Wl1p[i] = Wl1[i] + Wl1[128 * 32 + i];
}

// ---------------- K1: node kernel ----------------
// per 16-node tile: pre_s -> q, pre_v, vnorm, gating MLP g, xs3, xv3
__global__ __launch_bounds__(192) void k_node(
    const float* __restrict__ x,
    const float* __restrict__ Wpre_s, const float* __restrict__ bpre_s,
    const float* __restrict__ Wpre_v,
    const float* __restrict__ Wg1, const float* __restrict__ bg1,
    const float* __restrict__ Wg2, const float* __restrict__ bg2,
    const float* __restrict__ Wn_s, const float* __restrict__ bn_s,
    const float* __restrict__ Wn_v,
    const float* __restrict__ Wl1p,
    float* __restrict__ preV, float* __restrict__ qv,
    float* __restrict__ xs3, float* __restrict__ xv3,
    int nNodes)
{
    __shared__ float sF0[16 * 192];  // xs | vnorm  (f0); later xv2
    __shared__ float sXV[16 * 192];  // xv
    __shared__ float sA[16 * 192];   // pre_s, then h1
    __shared__ float sB[16 * 192];   // g

    const int t = threadIdx.x;
    const int n0 = blockIdx.x * 16;

    // ---- load x tile ----
    for (int idx = t; idx < 16 * 320; idx += 192) {
        int i = idx / 320, j = idx - i * 320;
        int n = n0 + i;
        float v = (n < nNodes) ? x[(size_t)n * 320 + j] : 0.0f;
        if (j < 128) sF0[i * 192 + j] = v;
        else         sXV[i * 192 + (j - 128)] = v;
    }
    __syncthreads();

    // ---- vnorm into sF0[:,128:192] ----
    for (int task = t; task < 16 * 64; task += 192) {
        int i = task >> 6, u = task & 63;
        float a = sXV[i * 192 + u * 3];
        float b = sXV[i * 192 + u * 3 + 1];
        float c = sXV[i * 192 + u * 3 + 2];
        sF0[i * 192 + 128 + u] = sqrtf(a * a + b * b + c * c + 1e-12f);
    }

    // ---- pre_v (reads sXV only) ----
    {
        int c = t >> 6, o = t & 63;
        float acc[16];
#pragma unroll
        for (int i = 0; i < 16; ++i) acc[i] = 0.0f;
        for (int u = 0; u < 64; ++u) {
            float w = Wpre_v[u * 64 + o];
#pragma unroll
            for (int i = 0; i < 16; ++i) acc[i] += sXV[i * 192 + u * 3 + c] * w;
        }
#pragma unroll
        for (int i = 0; i < 16; ++i) {
            int n = n0 + i;
            if (n < nNodes) preV[(size_t)n * 192 + o * 3 + c] = acc[i] * INV_S64;
        }
    }
    __syncthreads();

    // ---- pre_s -> sA (threads 0..127) ----
    if (t < 128) {
        float acc[16];
#pragma unroll
        for (int i = 0; i < 16; ++i) acc[i] = 0.0f;
        for (int u = 0; u < 128; ++u) {
            float w = Wpre_s[u * 128 + t];
#pragma unroll
            for (int i = 0; i < 16; ++i) acc[i] += sF0[i * 192 + u] * w;
        }
        float b = bpre_s[t];
#pragma unroll
        for (int i = 0; i < 16; ++i) sA[i * 192 + t] = acc[i] * INV_S128 + b;
    }
    __syncthreads();

    // ---- q = pre_s @ Wl1p  (16x32 outputs) ----
    for (int task = t; task < 16 * 32; task += 192) {
        int i = task >> 5, o = task & 31;
        float a = 0.0f;
        for (int u = 0; u < 128; ++u) a += sA[i * 192 + u] * Wl1p[u * 32 + o];
        int n = n0 + i;
        if (n < nNodes) qv[(size_t)n * 32 + o] = a;
    }
    __syncthreads();

    // ---- g1: h1 = silu(f0 @ Wg1 + bg1) -> sA ----
    {
        float acc[16];
#pragma unroll
        for (int i = 0; i < 16; ++i) acc[i] = 0.0f;
        for (int u = 0; u < 192; ++u) {
            float w = Wg1[u * 192 + t];
#pragma unroll
            for (int i = 0; i < 16; ++i) acc[i] += sF0[i * 192 + u] * w;
        }
        float b = bg1[t];
        __syncthreads();   // sA (pre_s) fully consumed by q-phase
#pragma unroll
        for (int i = 0; i < 16; ++i) sA[i * 192 + t] = siluf(acc[i] + b);
    }
    __syncthreads();

    // ---- g2: g = h1 @ Wg2 + bg2 -> sB ----
    {
        float acc[16];
#pragma unroll
        for (int i = 0; i < 16; ++i) acc[i] = 0.0f;
        for (int u = 0; u < 192; ++u) {
            float w = Wg2[u * 192 + t];
#pragma unroll
            for (int i = 0; i < 16; ++i) acc[i] += sA[i * 192 + u] * w;
        }
        float b = bg2[t];
#pragma unroll
        for (int i = 0; i < 16; ++i) sB[i * 192 + t] = acc[i] + b;
    }
    __syncthreads();

    // ---- xs3 = g[:, :128] @ Wn_s * inv_s128 + bn_s  (threads 0..127) ----
    if (t < 128) {
        float acc[16];
#pragma unroll
        for (int i = 0; i < 16; ++i) acc[i] = 0.0f;
        for (int u = 0; u < 128; ++u) {
            float w = Wn_s[u * 128 + t];
#pragma unroll
            for (int i = 0; i < 16; ++i) acc[i] += sB[i * 192 + u] * w;
        }
        float b = bn_s[t];
#pragma unroll
        for (int i = 0; i < 16; ++i) {
            int n = n0 + i;
            if (n < nNodes) xs3[(size_t)n * 128 + t] = acc[i] * INV_S128 + b;
        }
    }

    // ---- xv2 = xv * g[:,128:]  -> sF0 (f0 no longer needed) ----
    {
        int u = t / 3;  // t in 0..191 -> (u = t/3, c = t%3)
#pragma unroll
        for (int i = 0; i < 16; ++i) {
            sF0[i * 192 + t] = sXV[i * 192 + t] * sB[i * 192 + 128 + u];
        }
    }
    __syncthreads();

    // ---- xv3 = einsum(xv2, Wn_v) * inv_s64 ----
    {
        int c = t >> 6, o = t & 63;
        float acc[16];
#pragma unroll
        for (int i = 0; i < 16; ++i) acc[i] = 0.0f;
        for (int u = 0; u < 64; ++u) {
            float w = Wn_v[u * 64 + o];
#pragma unroll
            for (int i = 0; i < 16; ++i) acc[i] += sF0[i * 192 + u * 3 + c] * w;
        }
#pragma unroll
        for (int i = 0; i < 16; ++i) {
            int n = n0 + i;
            if (n < nNodes) xv3[(size_t)n * 192 + o * 3 + c] = acc[i] * INV_S64;
        }
    }
}

// ---------------- K2: edge kernel ----------------
#define EB 8
__global__ __launch_bounds__(384) void k_edge(
    const int* __restrict__ ei,
    const float* __restrict__ ea,
    const float* __restrict__ esh,
    const float* __restrict__ Wf1, const float* __restrict__ Wf2,
    const float* __restrict__ Wl1, const float* __restrict__ Wl2,
    const float* __restrict__ preV, const float* __restrict__ qv,
    const float* __restrict__ xs3, const float* __restrict__ xv3,
    float* __restrict__ acc,
    int nEdges)
{
    __shared__ float sWf1[32 * 32];
    __shared__ float sWl1c[64 * 32];
    __shared__ float sEA[EB * 32];
    __shared__ float sSH[EB * 4];
    __shared__ float sIp1[EB * 64];
    __shared__ float sH[EB * 64];     // [e*64 + 0..31]=hA, [e*64 + 32..63]=hB
    __shared__ float sW[EB * 384];
    __shared__ int sDst[EB], sSrc[EB];

    const int t = threadIdx.x;

    // persistent per-thread weight columns
    float rWf2[32], rWl2[32];
#pragma unroll
    for (int u = 0; u < 32; ++u) {
        rWf2[u] = Wf2[u * 384 + t];
        rWl2[u] = Wl2[u * 384 + t];
    }
    for (int i = t; i < 32 * 32; i += 384) sWf1[i] = Wf1[i];
    for (int i = t; i < 64 * 32; i += 384) sWl1c[i] = Wl1[256 * 32 + i];

    const int ngroups = (nEdges + EB - 1) / EB;
    for (int g = blockIdx.x; g < ngroups; g += gridDim.x) {
        const int e0 = g * EB;
        __syncthreads();   // protect staging buffers from previous iteration

        // ---- stage per-edge small data ----
        if (t < EB * 32) {
            int e = t >> 5;
            sEA[t] = (e0 + e < nEdges) ? ea[(size_t)e0 * 32 + t] : 0.0f;
        } else if (t < EB * 32 + EB * 4) {
            int k = t - EB * 32;
            int e = k >> 2;
            sSH[k] = (e0 + e < nEdges) ? esh[(size_t)e0 * 4 + k] : 0.0f;
        } else if (t < EB * 32 + EB * 4 + EB) {
            int k = t - EB * 32 - EB * 4;
            sDst[k] = (e0 + k < nEdges) ? ei[e0 + k] : 0;
        } else if (t < EB * 32 + EB * 4 + 2 * EB) {
            int k = t - EB * 32 - EB * 4 - EB;
            sSrc[k] = (e0 + k < nEdges) ? ei[nEdges + e0 + k] : 0;
        }
        __syncthreads();

        // ---- ip1 ----
        for (int task = t; task < EB * 64; task += 384) {
            int e = task >> 6, u = task & 63;
            const float* pd = preV + (size_t)sDst[e] * 192 + u * 3;
            const float* ps = preV + (size_t)sSrc[e] * 192 + u * 3;
            sIp1[task] = (pd[0] * ps[0] + pd[1] * ps[1] + pd[2] * ps[2]) * (1.0f / 3.0f);
        }
        __syncthreads();

        // ---- hA / hB ----
        if (t < 256) {
            int e = t >> 5, o = t & 31;
            float a = qv[(size_t)sDst[e] * 32 + o];
#pragma unroll 8
            for (int u = 0; u < 64; ++u) a += sIp1[e * 64 + u] * sWl1c[u * 32 + o];
            sH[e * 64 + 32 + o] = sspf(a * INV_S320);
        } else {
#pragma unroll
            for (int k = 0; k < 2; ++k) {
                int task = (t - 256) + 128 * k;
                int e = task >> 5, o = task & 31;
                float a = 0.0f;
#pragma unroll 8
                for (int u = 0; u < 32; ++u) a += sEA[e * 32 + u] * sWf1[u * 32 + o];
                sH[e * 64 + o] = sspf(a * INV_S32);
            }
        }
        __syncthreads();

        // ---- w = (hA@Wf2) * (hB@Wl2) / 32, column t per thread ----
        for (int e = 0; e < EB; ++e) {
            float a = 0.0f, b = 0.0f;
#pragma unroll
            for (int u = 0; u < 32; ++u) {
                a += sH[e * 64 + u] * rWf2[u];
                b += sH[e * 64 + 32 + u] * rWl2[u];
            }
            sW[e * 384 + t] = a * b * (1.0f / 32.0f);
        }
        __syncthreads();

        // ---- elementwise tensor products + scatter-add ----
        for (int e = 0; e < EB; ++e) {
            if (e0 + e >= nEdges) break;
            int d = sDst[e], s = sSrc[e];
            float sh0 = sSH[e * 4 + 0];
            float sh1a = sSH[e * 4 + 1], sh1b = sSH[e * 4 + 2], sh1c = sSH[e * 4 + 3];
#pragma unroll
            for (int half = 0; half < 2; ++half) {
                int p = t + half * 384;
                float val;
                if (p < 128) {
                    val = 0.5f * sW[e * 384 + p] * xs3[(size_t)s * 128 + p] * sh0;
                } else if (p < 192) {
                    int j = p - 128;
                    const float* hv = xv3 + (size_t)s * 192 + j * 3;
                    float dot = hv[0] * sh1a + hv[1] * sh1b + hv[2] * sh1c;
                    val = 0.5f * sW[e * 384 + 320 + j] * dot * INV_S3F;
                } else {
                    int q2 = p - 192;
                    int m = q2 / 3, c = q2 - m * 3;
                    float shc = sSH[e * 4 + 1 + c];
                    if (m < 128) {
                        val = C1F * sW[e * 384 + 128 + m] * xs3[(size_t)s * 128 + m] * shc;
                    } else {
                        int j = m - 128;
                        val = C1F * sW[e * 384 + 256 + j] * xv3[(size_t)s * 192 + j * 3 + c] * sh0;
                    }
                }
                atomicAdd(&acc[(size_t)d * 768 + p], val);
            }
        }
    }
}

// ---------------- K3: output kernel ----------------
__global__ __launch_bounds__(384) void k_out(
    const float* __restrict__ acc,
    const float* __restrict__ Wo_s, const float* __restrict__ bo_s,
    const float* __restrict__ Wo_v,
    float* __restrict__ out, int nNodes)
{
    __shared__ float sAcc[16 * 768];
    const int t = threadIdx.x;
    const int n0 = blockIdx.x * 16;

    for (int idx = t; idx < 16 * 768; idx += 384) {
        int i = idx / 768;
        int n = n0 + i;
        sAcc[idx] = (n < nNodes) ? acc[(size_t)n0 * 768 + idx] : 0.0f;
    }
    __syncthreads();

    // outs = ns @ Wo_s * inv_s192 + bo_s
    if (t < 256) {
        float a[16];
#pragma unroll
        for (int i = 0; i < 16; ++i) a[i] = 0.0f;
        for (int u = 0; u < 192; ++u) {
            float w = Wo_s[u * 256 + t];
#pragma unroll
            for (int i = 0; i < 16; ++i) a[i] += sAcc[i * 768 + u] * w;
        }
        float b = bo_s[t];
#pragma unroll
        for (int i = 0; i < 16; ++i) {
            int n = n0 + i;
            if (n < nNodes) out[(size_t)n * 640 + t] = a[i] * INV_S192 + b;
        }
    }

    // outv = einsum(nv, Wo_v) * inv_s192
    {
        int o = t & 127, c = t >> 7;
        float a[16];
#pragma unroll
        for (int i = 0; i < 16; ++i) a[i] = 0.0f;
        for (int u = 0; u < 192; ++u) {
            float w = Wo_v[u * 128 + o];
#pragma unroll
            for (int i = 0; i < 16; ++i) a[i] += sAcc[i * 768 + 192 + u * 3 + c] * w;
        }
#pragma unroll
        for (int i = 0; i < 16; ++i) {
            int n = n0 + i;
            if (n < nNodes) out[(size_t)n * 640 + 256 + o * 3 + c] = a[i] * INV_S192;
        }
    }
}

// ---------------- launcher ----------------
extern "C" void kernel_launch(void* const* d_in, const int* in_sizes, int n_in,
                              void* d_out, int out_size, void* d_ws, size_t ws_size,
                              hipStream_t stream)
{
    const float* x      = (const float*)d_in[0];
    const int*   ei     = (const int*)d_in[1];     // harness converts integer inputs to int32
    const float* ea     = (const float*)d_in[2];
    const float* esh    = (const float*)d_in[3];
    const float* Wpre_s = (const float*)d_in[4];
    const float* bpre_s = (const float*)d_in[5];
    const float* Wpre_v = (const float*)d_in[6];
    const float* Wg1    = (const float*)d_in[7];
    const float* bg1    = (const float*)d_in[8];
    const float* Wg2    = (const float*)d_in[9];
    const float* bg2    = (const float*)d_in[10];
    const float* Wn_s   = (const float*)d_in[11];
    const float* bn_s   = (const float*)d_in[12];
    const float* Wn_v   = (const float*)d_in[13];
    const float* Wf1    = (const float*)d_in[14];
    const float* Wf2    = (const float*)d_in[15];
    const float* Wl1    = (const float*)d_in[16];
    const float* Wl2    = (const float*)d_in[17];
    const float* Wo_s   = (const float*)d_in[18];
    const float* bo_s   = (const float*)d_in[19];
    const float* Wo_v   = (const float*)d_in[20];

    const int nNodes = in_sizes[0] / 320;
    const int nEdges = in_sizes[2] / 32;

    float* ws = (float*)d_ws;
    size_t off = 0;
    float* preV = ws + off; off += (size_t)nNodes * 192;
    float* qv   = ws + off; off += (size_t)nNodes * 32;
    float* xs3  = ws + off; off += (size_t)nNodes * 128;
    float* xv3  = ws + off; off += (size_t)nNodes * 192;
    float* Wl1p = ws + off; off += 128 * 32;
    float* accb = ws + off; off += (size_t)nNodes * 768;

    // zero the scatter accumulator (ws is poisoned 0xAA before every launch)
    {
        int n4 = (nNodes * 768) / 4;
        k_zero<<<2048, 256, 0, stream>>>((float4*)accb, n4);
    }

    k_prep<<<(128 * 32 + 255) / 256, 256, 0, stream>>>(Wl1, Wl1p);

    int nodeBlocks = (nNodes + 15) / 16;
    k_node<<<nodeBlocks, 192, 0, stream>>>(
        x, Wpre_s, bpre_s, Wpre_v, Wg1, bg1, Wg2, bg2,
        Wn_s, bn_s, Wn_v, Wl1p, preV, qv, xs3, xv3, nNodes);

    k_edge<<<1280, 384, 0, stream>>>(
        ei, ea, esh, Wf1, Wf2, Wl1, Wl2, preV, qv, xs3, xv3, accb, nEdges);

    k_out<<<nodeBlocks, 384, 0, stream>>>(accb, Wo_s, bo_s, Wo_v, (float*)d_out, nNodes);
}